// Round 5
// baseline (113.856 us; speedup 1.0000x reference)
//
#include <hip/hip_runtime.h>
#include <hip/hip_bf16.h>

constexpr int L = 12;
constexpr int B = 4, T = 2048, H = 16, D = 64;
constexpr int NPOS = B * T * H;                     // 131072 positions
constexpr long long SLAYER = (long long)NPOS * D;   // elements per layer slice
constexpr int PW = 16;                              // positions per wave

typedef __attribute__((ext_vector_type(8))) short bf16x8;
typedef __attribute__((ext_vector_type(4))) float f32x4;

__device__ __forceinline__ short f2bf(float f) {
  union { __hip_bfloat16 h; short s; } u;
  u.h = __float2bfloat16(f);
  return u.s;
}

// MT[n][k] = M[k][n] = sum_e Wq[e][k] * Wk[e][n], stored bf16 (8 KB, L2-hot).
__global__ __launch_bounds__(64) void cla_precompute_MT(
    const float* __restrict__ Wq, const float* __restrict__ Wk,
    short* __restrict__ MT) {
  const int n = blockIdx.x;
  const int k = threadIdx.x;
  float acc = 0.f;
  #pragma unroll
  for (int e = 0; e < D; ++e)
    acc = fmaf(Wq[e * D + k], Wk[e * D + n], acc);
  MT[n * D + k] = f2bf(acc);
}

// Full-wave (64-lane) sum, broadcast to all lanes. All-VALU (DPP + readlane).
// HW-verified correct in round 2's passing run.
template <int CTRL, int ROWM>
__device__ __forceinline__ float dpp_add(float x) {
  int moved = __builtin_amdgcn_update_dpp(0, __float_as_int(x), CTRL, ROWM, 0xF,
                                          false);
  return x + __int_as_float(moved);
}
__device__ __forceinline__ float wave_sum_bcast(float x) {
  x = dpp_add<0x111, 0xF>(x);  // row_shr:1
  x = dpp_add<0x112, 0xF>(x);  // row_shr:2
  x = dpp_add<0x114, 0xF>(x);  // row_shr:4
  x = dpp_add<0x118, 0xF>(x);  // row_shr:8   -> lane15 of each row = row sum
  x = dpp_add<0x142, 0xA>(x);  // row_bcast15 -> lane31 += , lane63 +=
  x = dpp_add<0x143, 0xC>(x);  // row_bcast31 -> lane63 = total
  return __int_as_float(__builtin_amdgcn_readlane(__float_as_int(x), 63));
}

__global__ __launch_bounds__(256, 8) void cla_main(
    const float* __restrict__ cur, const float* __restrict__ all,
    const short* __restrict__ MT, const float* __restrict__ scales,
    const float* __restrict__ temperature, float* __restrict__ out) {
  __shared__ float qlds[4][PW * D];   // per-wave q tile (16 KB / block)

  const int lane = threadIdx.x & 63;
  const int w    = threadIdx.x >> 6;
  const int wid  = blockIdx.x * 4 + w;
  const int pos0 = wid * PW;

  const int ncol = lane & 15;
  const int kq   = lane >> 4;

  const float inv_scale = 1.0f / (8.0f * fabsf(temperature[0]));  // sqrt(64)=8

  // ---- Phase 1: Q = X * M via MFMA (16 positions per wave) ----
  // A-frags: lane (ncol,kq) holds x[pos0+ncol][kc*32+kq*8 .. +8) as bf16.
  bf16x8 af[2];
  {
    const float* xb = cur + (size_t)(pos0 + ncol) * D + kq * 8;
    #pragma unroll
    for (int kc = 0; kc < 2; ++kc) {
      const float4 xlo = *(const float4*)(xb + kc * 32);
      const float4 xhi = *(const float4*)(xb + kc * 32 + 4);
      short a8[8] = {f2bf(xlo.x), f2bf(xlo.y), f2bf(xlo.z), f2bf(xlo.w),
                     f2bf(xhi.x), f2bf(xhi.y), f2bf(xhi.z), f2bf(xhi.w)};
      __builtin_memcpy(&af[kc], a8, 16);
    }
  }

  // Per nt: stream B-frags from global (L2-hot), retire acc immediately.
  #pragma unroll
  for (int nt = 0; nt < 4; ++nt) {
    f32x4 acc = {};
    #pragma unroll
    for (int kc = 0; kc < 2; ++kc) {
      const bf16x8 bm =
          *(const bf16x8*)(MT + (nt * 16 + ncol) * D + kc * 32 + kq * 8);
      acc = __builtin_amdgcn_mfma_f32_16x16x32_bf16(af[kc], bm, acc, 0, 0, 0);
    }
    // C layout: row(pos)=4*kq+r, col(n)=nt*16+ncol. Fold inv_scale in.
    #pragma unroll
    for (int r = 0; r < 4; ++r)
      qlds[w][(4 * kq + r) * D + nt * 16 + ncol] = acc[r] * inv_scale;
  }
  // Same-wave LDS write->read dependency; compiler inserts lgkmcnt waits.

  // ---- Phase 2: stream all_layers, ONE position per iteration ----
  // lane = d-component; y[l] is 1 VGPR each; weights wave-uniform.
  for (int it = 0; it < PW; ++it) {
    const size_t pbase = (size_t)(pos0 + it) * D;   // uniform
    const float q = qlds[w][it * D + lane];         // ds_read_b32, no conflict

    float y[L];
    #pragma unroll
    for (int l = 0; l < L; ++l) {
      const float* p = all + (size_t)l * SLAYER + pbase;  // uniform pointer
      y[l] = p[lane];                                     // 256 B coalesced
    }

    float sc[L];
    #pragma unroll
    for (int l = 0; l < L; ++l)
      sc[l] = wave_sum_bcast(q * y[l]);   // inv_scale folded into q

    // Softmax over L on wave-uniform values (redundant per lane, cheap).
    float mx = sc[0];
    #pragma unroll
    for (int l = 1; l < L; ++l) mx = fmaxf(mx, sc[l]);
    float sum = 0.f;
    #pragma unroll
    for (int l = 0; l < L; ++l) { sc[l] = __expf(sc[l] - mx); sum += sc[l]; }
    const float inv_sum = 1.0f / sum;

    float ssum = 0.f;
    #pragma unroll
    for (int l = 0; l < L; ++l) {
      sc[l] = sc[l] * inv_sum * scales[l];   // attn * scales
      ssum += sc[l];
    }
    const float r = 1.0f / (ssum + 1e-6f);

    float o = 0.f;
    #pragma unroll
    for (int l = 0; l < L; ++l) o = fmaf(sc[l] * r * scales[l], y[l], o);

    out[pbase + lane] = o;
  }
}

extern "C" void kernel_launch(void* const* d_in, const int* in_sizes, int n_in,
                              void* d_out, int out_size, void* d_ws, size_t ws_size,
                              hipStream_t stream) {
  const float* cur    = (const float*)d_in[0];
  const float* all    = (const float*)d_in[1];
  const float* Wq     = (const float*)d_in[2];
  const float* Wk     = (const float*)d_in[3];
  const float* scales = (const float*)d_in[4];
  const float* temp   = (const float*)d_in[5];
  short* MT = (short*)d_ws;   // 8 KB scratch: (Wq^T Wk)^T in bf16

  cla_precompute_MT<<<64, 64, 0, stream>>>(Wq, Wk, MT);

  const int nwaves  = NPOS / PW;    // 8192 waves
  const int nblocks = nwaves / 4;   // 2048 blocks of 256 threads
  cla_main<<<nblocks, 256, 0, stream>>>(cur, all, MT, scales, temp,
                                        (float*)d_out);
}

// Round 6
// 100.552 us; speedup vs baseline: 1.1323x; 1.1323x over previous
//
#include <hip/hip_runtime.h>
#include <hip/hip_bf16.h>

constexpr int L = 12;
constexpr int B = 4, T = 2048, H = 16, D = 64;
constexpr int NPOS = B * T * H;                     // 131072 positions
constexpr long long SLAYER = (long long)NPOS * D;   // elements per layer slice
constexpr int PW = 16;                              // positions per wave
constexpr int NG = 3, GL = 4;                       // 3 layer-groups of 4

typedef __attribute__((ext_vector_type(8))) short bf16x8;
typedef __attribute__((ext_vector_type(4))) float f32x4;

__device__ __forceinline__ short f2bf(float f) {
  union { __hip_bfloat16 h; short s; } u;
  u.h = __float2bfloat16(f);
  return u.s;
}

// MT[n][k] = M[k][n] = sum_e Wq[e][k] * Wk[e][n], stored bf16 (8 KB, L2-hot).
__global__ __launch_bounds__(64) void cla_precompute_MT(
    const float* __restrict__ Wq, const float* __restrict__ Wk,
    short* __restrict__ MT) {
  const int n = blockIdx.x;
  const int k = threadIdx.x;
  float acc = 0.f;
  #pragma unroll
  for (int e = 0; e < D; ++e)
    acc = fmaf(Wq[e * D + k], Wk[e * D + n], acc);
  MT[n * D + k] = f2bf(acc);
}

// 16-lane-row sum via DPP row_ror — VALU pipe. HW-verified (R3/R4 passed).
template <int CTRL>
__device__ __forceinline__ float ror_add(float x) {
  int moved = __builtin_amdgcn_update_dpp(0, __float_as_int(x), CTRL, 0xF, 0xF,
                                          false);
  return x + __int_as_float(moved);
}
__device__ __forceinline__ float row_sum16(float x) {
  x = ror_add<0x121>(x);
  x = ror_add<0x122>(x);
  x = ror_add<0x124>(x);
  x = ror_add<0x128>(x);
  return x;
}

__global__ __launch_bounds__(256, 2) void cla_main(
    const float* __restrict__ cur, const float* __restrict__ all,
    const short* __restrict__ MT, const float* __restrict__ scales,
    const float* __restrict__ temperature, float* __restrict__ out) {
  __shared__ float qlds[4][PW * D];   // per-wave q tile (16 KB / block)

  const int lane = threadIdx.x & 63;
  const int w    = threadIdx.x >> 6;
  const int wid  = blockIdx.x * 4 + w;
  const int pos0 = wid * PW;
  const int ncol = lane & 15;
  const int kq   = lane >> 4;

  // Streaming base: lane's float4 slot within the wave's 16-position block.
  const size_t sbase = (size_t)pos0 * D + (size_t)lane * 4;

  // ---- Prologue: issue group-0 y loads; latency hides under Phase 1 ----
  float4 yb[2][GL][4];   // [buffer][layer-in-group][quad] — all static indices
  #pragma unroll
  for (int i = 0; i < GL; ++i) {
    const float* p = all + (size_t)i * SLAYER + sbase;
    #pragma unroll
    for (int t = 0; t < 4; ++t)
      yb[0][i][t] = *(const float4*)(p + t * 256);
  }

  const float inv_scale = 1.0f / (8.0f * fabsf(temperature[0]));  // sqrt(64)=8

  // ---- Phase 1: Q = X * M via MFMA (verified in R4/R5) ----
  bf16x8 af[2];
  {
    const float* xb = cur + (size_t)(pos0 + ncol) * D + kq * 8;
    #pragma unroll
    for (int kc = 0; kc < 2; ++kc) {
      const float4 xlo = *(const float4*)(xb + kc * 32);
      const float4 xhi = *(const float4*)(xb + kc * 32 + 4);
      short a8[8] = {f2bf(xlo.x), f2bf(xlo.y), f2bf(xlo.z), f2bf(xlo.w),
                     f2bf(xhi.x), f2bf(xhi.y), f2bf(xhi.z), f2bf(xhi.w)};
      __builtin_memcpy(&af[kc], a8, 16);
    }
  }
  #pragma unroll
  for (int nt = 0; nt < 4; ++nt) {
    f32x4 acc = {};
    #pragma unroll
    for (int kc = 0; kc < 2; ++kc) {
      const bf16x8 bm =
          *(const bf16x8*)(MT + (nt * 16 + ncol) * D + kc * 32 + kq * 8);
      acc = __builtin_amdgcn_mfma_f32_16x16x32_bf16(af[kc], bm, acc, 0, 0, 0);
    }
    #pragma unroll
    for (int r = 0; r < 4; ++r)
      qlds[w][(4 * kq + r) * D + nt * 16 + ncol] = acc[r] * inv_scale;
  }
  // Same-wave LDS write->read; compiler inserts lgkmcnt waits, no barrier.

  // q for all 4 quads into registers (16 VGPRs).
  const int gq = lane >> 4;
  const int j  = lane & 15;
  float4 q[4];
  #pragma unroll
  for (int t = 0; t < 4; ++t)
    q[t] = *(const float4*)&qlds[w][(t * 4 + gq) * D + 4 * j];

  float scl[L], scl2[L];
  #pragma unroll
  for (int l = 0; l < L; ++l) {
    scl[l]  = scales[l];
    scl2[l] = scl[l] * scl[l];
  }

  // Online-softmax state per quad: out = N / (A + 1e-6*S),
  // N = sum scl^2*e^z*y, A = sum scl*e^z, S = sum e^z, z = sc - running max.
  float m[4], S[4], A[4];
  f32x4 N[4];
  #pragma unroll
  for (int t = 0; t < 4; ++t) {
    m[t] = -3.0e38f;
    S[t] = 0.f;
    A[t] = 0.f;
    N[t] = (f32x4){0.f, 0.f, 0.f, 0.f};
  }

  #pragma unroll
  for (int gi = 0; gi < NG; ++gi) {
    // Prefetch next group into the other buffer (in flight during compute).
    if (gi + 1 < NG) {
      #pragma unroll
      for (int i = 0; i < GL; ++i) {
        const float* p = all + (size_t)((gi + 1) * GL + i) * SLAYER + sbase;
        #pragma unroll
        for (int t = 0; t < 4; ++t)
          yb[(gi + 1) & 1][i][t] = *(const float4*)(p + t * 256);
      }
    }

    // Compute current group.
    #pragma unroll
    for (int t = 0; t < 4; ++t) {
      float sc[GL];
      #pragma unroll
      for (int i = 0; i < GL; ++i) {
        const float4 y = yb[gi & 1][i][t];
        const float s =
            q[t].x * y.x + q[t].y * y.y + q[t].z * y.z + q[t].w * y.w;
        sc[i] = row_sum16(s);   // inv_scale folded into q
      }
      float gm = sc[0];
      #pragma unroll
      for (int i = 1; i < GL; ++i) gm = fmaxf(gm, sc[i]);
      const float mn = fmaxf(m[t], gm);
      const float c  = __expf(m[t] - mn);   // first group: exp(-huge) = 0
      m[t] = mn;

      float e[GL];
      float dS = 0.f, dA = 0.f;
      #pragma unroll
      for (int i = 0; i < GL; ++i) {
        e[i] = __expf(sc[i] - mn);
        dS += e[i];
        dA += scl[gi * GL + i] * e[i];
      }
      S[t] = S[t] * c + dS;
      A[t] = A[t] * c + dA;

      float ax = 0.f, ay = 0.f, az = 0.f, aw = 0.f;
      #pragma unroll
      for (int i = 0; i < GL; ++i) {
        const float wl = scl2[gi * GL + i] * e[i];
        const float4 y = yb[gi & 1][i][t];
        ax = fmaf(wl, y.x, ax);
        ay = fmaf(wl, y.y, ay);
        az = fmaf(wl, y.z, az);
        aw = fmaf(wl, y.w, aw);
      }
      N[t][0] = N[t][0] * c + ax;
      N[t][1] = N[t][1] * c + ay;
      N[t][2] = N[t][2] * c + az;
      N[t][3] = N[t][3] * c + aw;
    }
  }

  // Epilogue: finalize and store (4 x 1 KB coalesced).
  #pragma unroll
  for (int t = 0; t < 4; ++t) {
    const float r = 1.0f / (A[t] + 1e-6f * S[t]);
    *(float4*)(out + sbase + t * 256) =
        make_float4(N[t][0] * r, N[t][1] * r, N[t][2] * r, N[t][3] * r);
  }
}

extern "C" void kernel_launch(void* const* d_in, const int* in_sizes, int n_in,
                              void* d_out, int out_size, void* d_ws, size_t ws_size,
                              hipStream_t stream) {
  const float* cur    = (const float*)d_in[0];
  const float* all    = (const float*)d_in[1];
  const float* Wq     = (const float*)d_in[2];
  const float* Wk     = (const float*)d_in[3];
  const float* scales = (const float*)d_in[4];
  const float* temp   = (const float*)d_in[5];
  short* MT = (short*)d_ws;   // 8 KB scratch: (Wq^T Wk)^T in bf16

  cla_precompute_MT<<<64, 64, 0, stream>>>(Wq, Wk, MT);

  const int nwaves  = NPOS / PW;    // 8192 waves
  const int nblocks = nwaves / 4;   // 2048 blocks of 256 threads
  cla_main<<<nblocks, 256, 0, stream>>>(cur, all, MT, scales, temp,
                                        (float*)d_out);
}